// Round 4
// baseline (9195.673 us; speedup 1.0000x reference)
//
#include <hip/hip_runtime.h>
#include <math.h>

#define B_   32
#define P_   196
#define F_   2048
#define E_   512
#define H_   512
#define V_   10000
#define T_   20
#define NBLK 256   // persistent grid

typedef unsigned short ushort_t;
typedef ushort_t u16x8 __attribute__((ext_vector_type(8)));
typedef ushort_t u16x2 __attribute__((ext_vector_type(2)));
typedef short    bf16x8 __attribute__((ext_vector_type(8)));
typedef float    f32x4  __attribute__((ext_vector_type(4)));

__device__ __forceinline__ ushort_t bf_rne(float x) {
    union { float f; unsigned u; } v; v.f = x;
    unsigned r = v.u + 0x7FFFu + ((v.u >> 16) & 1u);
    return (ushort_t)(r >> 16);
}
__device__ __forceinline__ float b2f(ushort_t u) {
    union { unsigned u; float f; } v; v.u = ((unsigned)u) << 16;
    return v.f;
}

// ---------------------------------------------------------------------------
// One-time conversion mega-kernel: all bf16 converts / extracts / transposes /
// gathers in a single node (block-range dispatch). 13125 blocks x 256 thr.
// ---------------------------------------------------------------------------
__global__ __launch_bounds__(256)
void cvt_all_kernel(const float* __restrict__ feat, const float* __restrict__ enc_W,
                    const float* __restrict__ fc_W, const float* __restrict__ dec_W,
                    const float* __restrict__ W_ih, const float* __restrict__ W_hh,
                    const float* __restrict__ emb, const int* __restrict__ captions,
                    const float* __restrict__ b_ih, const float* __restrict__ b_hh,
                    ushort_t* __restrict__ featB, ushort_t* __restrict__ encWB,
                    ushort_t* __restrict__ fcWB, ushort_t* __restrict__ decWB,
                    ushort_t* __restrict__ WihCB, ushort_t* __restrict__ WihEB,
                    ushort_t* __restrict__ WhhT, ushort_t* __restrict__ XB,
                    float* __restrict__ bsum, float* __restrict__ zbuf)
{
    const int blk = blockIdx.x, tid = threadIdx.x;
    if (blk < 6272) {                       // featB flat 12,845,056
        size_t i = (size_t)blk * 2048 + tid * 8;
        float4 a = *(const float4*)&feat[i], b = *(const float4*)&feat[i + 4];
        u16x8 o; o[0]=bf_rne(a.x); o[1]=bf_rne(a.y); o[2]=bf_rne(a.z); o[3]=bf_rne(a.w);
        o[4]=bf_rne(b.x); o[5]=bf_rne(b.y); o[6]=bf_rne(b.z); o[7]=bf_rne(b.w);
        *(u16x8*)&featB[i] = o;
    } else if (blk < 6784) {                // encWB flat 1,048,576
        size_t i = (size_t)(blk - 6272) * 2048 + tid * 8;
        float4 a = *(const float4*)&enc_W[i], b = *(const float4*)&enc_W[i + 4];
        u16x8 o; o[0]=bf_rne(a.x); o[1]=bf_rne(a.y); o[2]=bf_rne(a.z); o[3]=bf_rne(a.w);
        o[4]=bf_rne(b.x); o[5]=bf_rne(b.y); o[6]=bf_rne(b.z); o[7]=bf_rne(b.w);
        *(u16x8*)&encWB[i] = o;
    } else if (blk < 9284) {                // fcWB flat 5,120,000
        size_t i = (size_t)(blk - 6784) * 2048 + tid * 8;
        float4 a = *(const float4*)&fc_W[i], b = *(const float4*)&fc_W[i + 4];
        u16x8 o; o[0]=bf_rne(a.x); o[1]=bf_rne(a.y); o[2]=bf_rne(a.z); o[3]=bf_rne(a.w);
        o[4]=bf_rne(b.x); o[5]=bf_rne(b.y); o[6]=bf_rne(b.z); o[7]=bf_rne(b.w);
        *(u16x8*)&fcWB[i] = o;
    } else if (blk < 9412) {                // decWB flat 262,144
        size_t i = (size_t)(blk - 9284) * 2048 + tid * 8;
        float4 a = *(const float4*)&dec_W[i], b = *(const float4*)&dec_W[i + 4];
        u16x8 o; o[0]=bf_rne(a.x); o[1]=bf_rne(a.y); o[2]=bf_rne(a.z); o[3]=bf_rne(a.w);
        o[4]=bf_rne(b.x); o[5]=bf_rne(b.y); o[6]=bf_rne(b.z); o[7]=bf_rne(b.w);
        *(u16x8*)&decWB[i] = o;
    } else if (blk < 11460) {               // WihCB = bf16(W_ih[:, 512:2560]) [2048,2048]
        int j = blk - 9412, f = tid * 8;
        const float* s = &W_ih[(size_t)j * 2560 + 512 + f];
        float4 a = *(const float4*)&s[0], b = *(const float4*)&s[4];
        u16x8 o; o[0]=bf_rne(a.x); o[1]=bf_rne(a.y); o[2]=bf_rne(a.z); o[3]=bf_rne(a.w);
        o[4]=bf_rne(b.x); o[5]=bf_rne(b.y); o[6]=bf_rne(b.z); o[7]=bf_rne(b.w);
        *(u16x8*)&WihEB[0]; // no-op keep compiler honest
        *(u16x8*)&WihCB[(size_t)j * 2048 + f] = o;
    } else if (blk < 11972) {               // WihEB = bf16(W_ih[:, 0:512]) [2048,512]
        size_t idx = (size_t)(blk - 11460) * 2048 + tid * 8;
        int j = (int)(idx >> 9), f = (int)(idx & 511);
        const float* s = &W_ih[(size_t)j * 2560 + f];
        float4 a = *(const float4*)&s[0], b = *(const float4*)&s[4];
        u16x8 o; o[0]=bf_rne(a.x); o[1]=bf_rne(a.y); o[2]=bf_rne(a.z); o[3]=bf_rne(a.w);
        o[4]=bf_rne(b.x); o[5]=bf_rne(b.y); o[6]=bf_rne(b.z); o[7]=bf_rne(b.w);
        *(u16x8*)&WihEB[idx] = o;
    } else if (blk < 12484) {               // WhhT[k][j] = bf16(W_hh[j][k]) [512,2048]
        int k = blk - 11972, j0 = tid * 8;
        u16x8 o;
#pragma unroll
        for (int q = 0; q < 8; q++) o[q] = bf_rne(W_hh[(size_t)(j0 + q) * 512 + k]);
        *(u16x8*)&WhhT[(size_t)k * 2048 + j0] = o;
    } else if (blk < 13124) {               // XB[m] = bf16(emb[captions]), m = t*32+b
        int m = blk - 12484;
        int tt = m >> 5, b = m & 31;
        int cap = captions[b * T_ + tt];
        int i = tid * 2;
        u16x2 o;
        o[0] = bf_rne(emb[(size_t)cap * 512 + i]);
        o[1] = bf_rne(emb[(size_t)cap * 512 + i + 1]);
        *(u16x2*)&XB[(size_t)m * 512 + i] = o;
    } else {                                // bsum + zbuf (2048 each)
        int i = tid * 8;
#pragma unroll
        for (int q = 0; q < 8; q++) {
            bsum[i + q] = b_ih[i + q] + b_hh[i + q];
            zbuf[i + q] = 0.f;
        }
    }
}

// ---------------------------------------------------------------------------
// bf16 MFMA GEMM: C[m,n] = A[m,:].B[n,:] + bias[n], A/B bf16 K-major.
// 128x128 tile, 4 waves, 4x4 of 16x16x32 MFMA per wave.
// mode 0: bf16 store to Cb (plain).  mode 1: f32 store remap crow=(m&31)*20+(m>>5),
// guard n<N.  mode 2: f32 store plain.
// ---------------------------------------------------------------------------
__global__ __launch_bounds__(256)
void mfma_gemm_kernel(const ushort_t* __restrict__ A, const ushort_t* __restrict__ B,
                      const float* __restrict__ bias, ushort_t* __restrict__ Cb,
                      float* __restrict__ Cf, int K, int N, int mode)
{
    __shared__ ushort_t As[128][32];
    __shared__ ushort_t Bs[128][32];
    const int tid = threadIdx.x;
    const int m0 = blockIdx.x * 128, n0 = blockIdx.y * 128;
    const int wave = tid >> 6, lane = tid & 63;
    const int wm = (wave & 1) * 64, wn = (wave >> 1) * 64;
    const int lm = lane & 15, lk = (lane >> 4) * 8;

    f32x4 acc[4][4];
#pragma unroll
    for (int mt = 0; mt < 4; mt++)
#pragma unroll
        for (int nt = 0; nt < 4; nt++)
#pragma unroll
            for (int r = 0; r < 4; r++) acc[mt][nt][r] = 0.f;

    for (int k0 = 0; k0 < K; k0 += 32) {
#pragma unroll
        for (int i = 0; i < 2; i++) {
            int gi  = tid + i * 256;
            int row = gi >> 2;
            int gr  = (gi & 3) * 8;
            *(u16x8*)&As[row][gr] = *(const u16x8*)&A[(size_t)(m0 + row) * K + k0 + gr];
            int brow = n0 + row; if (brow >= N) brow = N - 1;
            *(u16x8*)&Bs[row][gr] = *(const u16x8*)&B[(size_t)brow * K + k0 + gr];
        }
        __syncthreads();
        bf16x8 af[4], bv[4];
#pragma unroll
        for (int mt = 0; mt < 4; mt++)
            af[mt] = *(const bf16x8*)&As[wm + mt * 16 + lm][lk];
#pragma unroll
        for (int nt = 0; nt < 4; nt++)
            bv[nt] = *(const bf16x8*)&Bs[wn + nt * 16 + lm][lk];
#pragma unroll
        for (int mt = 0; mt < 4; mt++)
#pragma unroll
            for (int nt = 0; nt < 4; nt++)
                acc[mt][nt] = __builtin_amdgcn_mfma_f32_16x16x32_bf16(
                    af[mt], bv[nt], acc[mt][nt], 0, 0, 0);
        __syncthreads();
    }

    const int rb = (lane >> 4) * 4;
#pragma unroll
    for (int nt = 0; nt < 4; nt++) {
        int n = n0 + wn + nt * 16 + lm;
        int nc = n < N ? n : N - 1;
        float bz = bias[nc];
#pragma unroll
        for (int mt = 0; mt < 4; mt++) {
            int mbase = m0 + wm + mt * 16 + rb;
#pragma unroll
            for (int r = 0; r < 4; r++) {
                float v = acc[mt][nt][r] + bz;
                int m = mbase + r;
                if (mode == 0) {
                    Cb[(size_t)m * N + n] = bf_rne(v);
                } else if (n < N) {
                    int crow = (mode == 1) ? ((m & 31) * 20 + (m >> 5)) : m;
                    Cf[(size_t)crow * N + n] = v;
                }
            }
        }
    }
}

// ---------------------------------------------------------------------------
// Grid barrier (sense via monotonically increasing generation).
// Requires all NBLK blocks co-resident: __launch_bounds__(256,2) gives
// capacity 2 blocks/CU x 256 CUs = 512 >= 256, so no deadlock regardless of
// placement. bar[0]=count, bar[1]=generation, zeroed by memset node per call.
// ---------------------------------------------------------------------------
__device__ __forceinline__ void grid_barrier(unsigned* bar) {
    __syncthreads();
    if (threadIdx.x == 0) {
        __threadfence();
        unsigned g = __hip_atomic_load(&bar[1], __ATOMIC_RELAXED, __HIP_MEMORY_SCOPE_AGENT);
        unsigned old = __hip_atomic_fetch_add(&bar[0], 1u, __ATOMIC_ACQ_REL, __HIP_MEMORY_SCOPE_AGENT);
        if (old == NBLK - 1) {
            __hip_atomic_store(&bar[0], 0u, __ATOMIC_RELAXED, __HIP_MEMORY_SCOPE_AGENT);
            __hip_atomic_fetch_add(&bar[1], 1u, __ATOMIC_RELEASE, __HIP_MEMORY_SCOPE_AGENT);
        } else {
            while (__hip_atomic_load(&bar[1], __ATOMIC_ACQUIRE, __HIP_MEMORY_SCOPE_AGENT) == g)
                __builtin_amdgcn_s_sleep(2);
        }
        __threadfence();
    }
    __syncthreads();
}

// ---------------------------------------------------------------------------
// Persistent 20-step decoder loop. 256 blocks x 256 thr.
// Per step t: phase-1 (blocks 0..31, block=b): pointwise h_t (c in regs),
//   dps = h.decW^T, energies from encPB, softmax -> alpha; write hF/hseqB.
// barrier; phase-2 (all blocks, (b,jc)): g[b,j] = xproj[t,b,j] (+biases)
//   + sum_k WhhT[k,j] h[b,k] + sum_p alpha[b,p] G[b,p,j]. barrier.
// ---------------------------------------------------------------------------
__global__ __launch_bounds__(256, 2)
void persist_kernel(float* __restrict__ gbuf,          // [32][2048] preact
                    float* __restrict__ hF,            // [32][512] f32
                    ushort_t* __restrict__ hseqB,      // [21][32][512] bf16
                    const ushort_t* __restrict__ encPB,// [6272][512]
                    const ushort_t* __restrict__ decWB,// [512][512]
                    const float* __restrict__ dec_b,
                    const float* __restrict__ full_W,
                    const float* __restrict__ full_b,
                    float* __restrict__ alpha,         // [32][200]
                    const ushort_t* __restrict__ GB,   // [6272][2048]
                    const ushort_t* __restrict__ WhhT, // [512][2048]
                    const float* __restrict__ xproj,   // [640][2048]
                    unsigned* __restrict__ bar)
{
    __shared__ float hs[512];
    __shared__ float fws[512];
    __shared__ float dps[512];
    __shared__ float es[200];
    __shared__ float al[200];
    __shared__ float hsh[512];

    const int tid = threadIdx.x;
    const int blk = blockIdx.x;
    const int b1 = blk;                 // phase-1 batch (blk < 32)
    const int b2 = blk >> 3;            // phase-2 batch
    const int jc = blk & 7;             // phase-2 j-chunk
    const int j  = jc * 256 + tid;

    float c0 = 0.f, c1 = 0.f;           // cell state, block-private (blk<32)

    if (blk < 32 && tid < 128)
        *(float4*)&fws[tid * 4] = *(const float4*)&full_W[tid * 4];

    for (int t = 0; t <= T_; t++) {
        // ================= phase 1 =================
        if (blk < 32) {
            if (t == 0) {
#pragma unroll
                for (int it = 0; it < 2; it++) {
                    int u = tid + it * 256;
                    hs[u] = 0.f;
                    hF[b1 * 512 + u] = 0.f;
                }
            } else {
#pragma unroll
                for (int it = 0; it < 2; it++) {
                    int u = tid + it * 256;
                    float gi = gbuf[b1 * 2048 + u];
                    float gf = gbuf[b1 * 2048 + 512 + u];
                    float gg = gbuf[b1 * 2048 + 1024 + u];
                    float go = gbuf[b1 * 2048 + 1536 + u];
                    float ig = 1.f / (1.f + expf(-gi));
                    float fg = 1.f / (1.f + expf(-gf));
                    float g_ = tanhf(gg);
                    float og = 1.f / (1.f + expf(-go));
                    float cold = it ? c1 : c0;
                    float cn = fg * cold + ig * g_;
                    float hn = og * tanhf(cn);
                    if (it) c1 = cn; else c0 = cn;
                    hs[u] = hn;
                    hF[b1 * 512 + u] = hn;
                    hseqB[(size_t)t * 16384 + b1 * 512 + u] = bf_rne(hn);
                }
            }
            if (t < T_) {
                __syncthreads();
                const int lane = tid & 63, wave = tid >> 6;
                const int g16 = lane >> 4, gl = lane & 15;
                // dps
#pragma unroll 4
                for (int q = 0; q < 32; q++) {
                    int a = wave * 128 + q * 4 + g16;
                    const ushort_t* wr = decWB + (size_t)a * 512;
                    float s = 0.f;
#pragma unroll
                    for (int jj = 0; jj < 4; jj++) {
                        u16x8 wv = *(const u16x8*)&wr[jj * 128 + gl * 8];
                        float4 h0 = *(float4*)&hs[jj * 128 + gl * 8];
                        float4 h1 = *(float4*)&hs[jj * 128 + gl * 8 + 4];
                        s += b2f(wv[0]) * h0.x + b2f(wv[1]) * h0.y
                           + b2f(wv[2]) * h0.z + b2f(wv[3]) * h0.w
                           + b2f(wv[4]) * h1.x + b2f(wv[5]) * h1.y
                           + b2f(wv[6]) * h1.z + b2f(wv[7]) * h1.w;
                    }
                    s += __shfl_xor(s, 1, 64); s += __shfl_xor(s, 2, 64);
                    s += __shfl_xor(s, 4, 64); s += __shfl_xor(s, 8, 64);
                    if (gl == 0) dps[a] = s + dec_b[a];
                }
                __syncthreads();
                // energies
                const float fb0 = full_b[0];
                for (int i = 0; i < 13; i++) {
                    int q = wave + 4 * i;
                    if (q >= 49) break;
                    int p = q * 4 + g16;
                    const ushort_t* ep = encPB + ((size_t)(b1 * P_) + p) * 512;
                    float s = 0.f;
#pragma unroll
                    for (int jj = 0; jj < 4; jj++) {
                        u16x8 ev = *(const u16x8*)&ep[jj * 128 + gl * 8];
                        float4 d0 = *(float4*)&dps[jj * 128 + gl * 8];
                        float4 d1 = *(float4*)&dps[jj * 128 + gl * 8 + 4];
                        float4 f0 = *(float4*)&fws[jj * 128 + gl * 8];
                        float4 f1 = *(float4*)&fws[jj * 128 + gl * 8 + 4];
                        s += fmaxf(b2f(ev[0]) + d0.x, 0.f) * f0.x
                           + fmaxf(b2f(ev[1]) + d0.y, 0.f) * f0.y
                           + fmaxf(b2f(ev[2]) + d0.z, 0.f) * f0.z
                           + fmaxf(b2f(ev[3]) + d0.w, 0.f) * f0.w
                           + fmaxf(b2f(ev[4]) + d1.x, 0.f) * f1.x
                           + fmaxf(b2f(ev[5]) + d1.y, 0.f) * f1.y
                           + fmaxf(b2f(ev[6]) + d1.z, 0.f) * f1.z
                           + fmaxf(b2f(ev[7]) + d1.w, 0.f) * f1.w;
                    }
                    s += __shfl_xor(s, 1, 64); s += __shfl_xor(s, 2, 64);
                    s += __shfl_xor(s, 4, 64); s += __shfl_xor(s, 8, 64);
                    if (gl == 0) es[p] = s + fb0;
                }
                __syncthreads();
                // softmax (wave 0)
                if (tid < 64) {
                    float v[4]; int pv[4]; int n = 0;
                    for (int q = 0; q < 4; q++) {
                        int p = tid + 64 * q;
                        if (p < P_) { pv[n] = p; v[n] = es[p]; n++; }
                    }
                    float m = -1e30f;
                    for (int q = 0; q < n; q++) m = fmaxf(m, v[q]);
#pragma unroll
                    for (int off = 32; off > 0; off >>= 1) m = fmaxf(m, __shfl_xor(m, off, 64));
                    float ssum = 0.f;
                    for (int q = 0; q < n; q++) { v[q] = expf(v[q] - m); ssum += v[q]; }
#pragma unroll
                    for (int off = 32; off > 0; off >>= 1) ssum += __shfl_xor(ssum, off, 64);
                    float rinv = 1.f / ssum;
                    for (int q = 0; q < n; q++) alpha[b1 * 200 + pv[q]] = v[q] * rinv;
                }
            }
        }
        if (t == T_) break;
        grid_barrier(bar);

        // ================= phase 2 =================
        {
            if (tid < P_) al[tid] = alpha[b2 * 200 + tid];
            hsh[tid]       = hF[b2 * 512 + tid];
            hsh[tid + 256] = hF[b2 * 512 + tid + 256];
            __syncthreads();

            float acc = xproj[(size_t)(t * 32 + b2) * 2048 + j];
            // W_hh part (transposed weight, coalesced)
            const ushort_t* wt = WhhT + j;
#pragma unroll 8
            for (int k = 0; k < 512; k++)
                acc += b2f(wt[(size_t)k * 2048]) * hsh[k];
            // attention-context part via G
            const ushort_t* gp = GB + (size_t)(b2 * P_) * 2048 + j;
#pragma unroll 4
            for (int p = 0; p < P_; p++)
                acc += al[p] * b2f(gp[(size_t)p * 2048]);
            gbuf[b2 * 2048 + j] = acc;
            __syncthreads();
        }
        grid_barrier(bar);
    }
}

// ---------------------------------------------------------------------------
extern "C" void kernel_launch(void* const* d_in, const int* in_sizes, int n_in,
                              void* d_out, int out_size, void* d_ws, size_t ws_size,
                              hipStream_t stream)
{
    (void)in_sizes; (void)n_in; (void)out_size; (void)ws_size;
    const float* feat   = (const float*)d_in[0];
    const int*   caps   = (const int*)  d_in[1];
    const float* emb    = (const float*)d_in[2];
    const float* W_ih   = (const float*)d_in[3];
    const float* b_ih   = (const float*)d_in[4];
    const float* W_hh   = (const float*)d_in[5];
    const float* b_hh   = (const float*)d_in[6];
    const float* fc_W   = (const float*)d_in[7];
    const float* fc_b   = (const float*)d_in[8];
    const float* enc_W  = (const float*)d_in[9];
    const float* enc_b  = (const float*)d_in[10];
    const float* dec_W  = (const float*)d_in[11];
    const float* dec_b  = (const float*)d_in[12];
    const float* full_W = (const float*)d_in[13];
    const float* full_b = (const float*)d_in[14];
    float* out = (float*)d_out;

    // workspace carve, ~90.2 MB (all offsets 128B-aligned)
    char* w = (char*)d_ws;
    ushort_t* featB = (ushort_t*)w;              w += 25690112;  // [6272][2048]
    ushort_t* encWB = (ushort_t*)w;              w += 2097152;   // [512][2048]
    ushort_t* fcWB  = (ushort_t*)w;              w += 10240000;  // [10000][512]
    ushort_t* decWB = (ushort_t*)w;              w += 524288;    // [512][512]
    ushort_t* WihCB = (ushort_t*)w;              w += 8388608;   // [2048][2048]
    ushort_t* WihEB = (ushort_t*)w;              w += 2097152;   // [2048][512]
    ushort_t* WhhT  = (ushort_t*)w;              w += 2097152;   // [512][2048]
    ushort_t* XB    = (ushort_t*)w;              w += 655360;    // [640][512]
    ushort_t* encPB = (ushort_t*)w;              w += 6422528;   // [6272][512]
    ushort_t* GB    = (ushort_t*)w;              w += 25690112;  // [6272][2048]
    float*    xproj = (float*)w;                 w += 5242880;   // [640][2048]
    float*    bsum  = (float*)w;                 w += 8192;      // [2048]
    float*    zbuf  = (float*)w;                 w += 8192;      // [2048]
    float*    hF    = (float*)w;                 w += 65536;     // [32][512]
    ushort_t* hseqB = (ushort_t*)w;              w += 688128;    // [21][32][512]
    float*    gbuf  = (float*)w;                 w += 262144;    // [32][2048]
    float*    alpha = (float*)w;                 w += 25600;     // [32][200]
    unsigned* bar   = (unsigned*)w;              w += 128;

    // zero barrier state (ws is re-poisoned before every replay)
    hipMemsetAsync(bar, 0, 128, stream);

    // one-time converts / extracts / transposes / gathers (1 node)
    cvt_all_kernel<<<13125, 256, 0, stream>>>(
        feat, enc_W, fc_W, dec_W, W_ih, W_hh, emb, caps, b_ih, b_hh,
        featB, encWB, fcWB, decWB, WihCB, WihEB, WhhT, XB, bsum, zbuf);

    // enc_proj: [6272,2048]x[512,2048]^T -> encPB bf16
    mfma_gemm_kernel<<<dim3(49, 4), 256, 0, stream>>>(
        featB, encWB, enc_b, encPB, nullptr, 2048, 512, 0);

    // G = feat . W_ih[:,512:]^T : [6272,2048]x[2048,2048]^T -> GB bf16
    mfma_gemm_kernel<<<dim3(49, 16), 256, 0, stream>>>(
        featB, WihCB, zbuf, GB, nullptr, 2048, 2048, 0);

    // xproj = X . W_ih[:,:512]^T + (b_ih+b_hh): [640,512]x[2048,512]^T -> f32
    mfma_gemm_kernel<<<dim3(5, 16), 256, 0, stream>>>(
        XB, WihEB, bsum, nullptr, xproj, 512, 2048, 2);

    // persistent 20-step recurrent loop (1 node)
    persist_kernel<<<NBLK, 256, 0, stream>>>(
        gbuf, hF, hseqB, encPB, decWB, dec_b, full_W, full_b,
        alpha, GB, WhhT, xproj, bar);

    // batched vocab FC: [640,512]x[10000,512]^T -> out (f32, remapped rows)
    mfma_gemm_kernel<<<dim3(5, 79), 256, 0, stream>>>(
        hseqB + 16384, fcWB, fc_b, nullptr, out, 512, V_, 1);
}

// Round 5
// 2103.065 us; speedup vs baseline: 4.3725x; 4.3725x over previous
//
#include <hip/hip_runtime.h>
#include <math.h>

#define B_   32
#define P_   196
#define F_   2048
#define E_   512
#define H_   512
#define V_   10000
#define T_   20
#define GSZ  5            // blocks per batch-element group (1 leader + 4 peers)
#define NBLK (B_ * GSZ)   // 160 persistent blocks

typedef unsigned short ushort_t;
typedef ushort_t u16x8 __attribute__((ext_vector_type(8)));
typedef ushort_t u16x2 __attribute__((ext_vector_type(2)));
typedef short    bf16x8 __attribute__((ext_vector_type(8)));
typedef float    f32x4  __attribute__((ext_vector_type(4)));

__device__ __forceinline__ ushort_t bf_rne(float x) {
    union { float f; unsigned u; } v; v.f = x;
    unsigned r = v.u + 0x7FFFu + ((v.u >> 16) & 1u);
    return (ushort_t)(r >> 16);
}
__device__ __forceinline__ float b2f(ushort_t u) {
    union { unsigned u; float f; } v; v.u = ((unsigned)u) << 16;
    return v.f;
}

// ---------------------------------------------------------------------------
// One-time conversion mega-kernel (1 node): bf16 converts / extracts /
// transposes / caption-gather. 13125 blocks x 256 thr.
// ---------------------------------------------------------------------------
__global__ __launch_bounds__(256)
void cvt_all_kernel(const float* __restrict__ feat, const float* __restrict__ enc_W,
                    const float* __restrict__ fc_W, const float* __restrict__ dec_W,
                    const float* __restrict__ W_ih, const float* __restrict__ W_hh,
                    const float* __restrict__ emb, const int* __restrict__ captions,
                    const float* __restrict__ b_ih, const float* __restrict__ b_hh,
                    ushort_t* __restrict__ featB, ushort_t* __restrict__ encWB,
                    ushort_t* __restrict__ fcWB, ushort_t* __restrict__ decWB,
                    ushort_t* __restrict__ WihCB, ushort_t* __restrict__ WihEB,
                    ushort_t* __restrict__ WhhT, ushort_t* __restrict__ XB,
                    float* __restrict__ bsum, float* __restrict__ zbuf)
{
    const int blk = blockIdx.x, tid = threadIdx.x;
    if (blk < 6272) {                       // featB flat
        size_t i = (size_t)blk * 2048 + tid * 8;
        float4 a = *(const float4*)&feat[i], b = *(const float4*)&feat[i + 4];
        u16x8 o; o[0]=bf_rne(a.x); o[1]=bf_rne(a.y); o[2]=bf_rne(a.z); o[3]=bf_rne(a.w);
        o[4]=bf_rne(b.x); o[5]=bf_rne(b.y); o[6]=bf_rne(b.z); o[7]=bf_rne(b.w);
        *(u16x8*)&featB[i] = o;
    } else if (blk < 6784) {                // encWB
        size_t i = (size_t)(blk - 6272) * 2048 + tid * 8;
        float4 a = *(const float4*)&enc_W[i], b = *(const float4*)&enc_W[i + 4];
        u16x8 o; o[0]=bf_rne(a.x); o[1]=bf_rne(a.y); o[2]=bf_rne(a.z); o[3]=bf_rne(a.w);
        o[4]=bf_rne(b.x); o[5]=bf_rne(b.y); o[6]=bf_rne(b.z); o[7]=bf_rne(b.w);
        *(u16x8*)&encWB[i] = o;
    } else if (blk < 9284) {                // fcWB
        size_t i = (size_t)(blk - 6784) * 2048 + tid * 8;
        float4 a = *(const float4*)&fc_W[i], b = *(const float4*)&fc_W[i + 4];
        u16x8 o; o[0]=bf_rne(a.x); o[1]=bf_rne(a.y); o[2]=bf_rne(a.z); o[3]=bf_rne(a.w);
        o[4]=bf_rne(b.x); o[5]=bf_rne(b.y); o[6]=bf_rne(b.z); o[7]=bf_rne(b.w);
        *(u16x8*)&fcWB[i] = o;
    } else if (blk < 9412) {                // decWB
        size_t i = (size_t)(blk - 9284) * 2048 + tid * 8;
        float4 a = *(const float4*)&dec_W[i], b = *(const float4*)&dec_W[i + 4];
        u16x8 o; o[0]=bf_rne(a.x); o[1]=bf_rne(a.y); o[2]=bf_rne(a.z); o[3]=bf_rne(a.w);
        o[4]=bf_rne(b.x); o[5]=bf_rne(b.y); o[6]=bf_rne(b.z); o[7]=bf_rne(b.w);
        *(u16x8*)&decWB[i] = o;
    } else if (blk < 11460) {               // WihCB = bf16(W_ih[:, 512:2560]) [2048][2048]
        int j = blk - 9412, f = tid * 8;
        const float* s = &W_ih[(size_t)j * 2560 + 512 + f];
        float4 a = *(const float4*)&s[0], b = *(const float4*)&s[4];
        u16x8 o; o[0]=bf_rne(a.x); o[1]=bf_rne(a.y); o[2]=bf_rne(a.z); o[3]=bf_rne(a.w);
        o[4]=bf_rne(b.x); o[5]=bf_rne(b.y); o[6]=bf_rne(b.z); o[7]=bf_rne(b.w);
        *(u16x8*)&WihCB[(size_t)j * 2048 + f] = o;
    } else if (blk < 11972) {               // WihEB = bf16(W_ih[:, 0:512]) [2048][512]
        size_t idx = (size_t)(blk - 11460) * 2048 + tid * 8;
        int j = (int)(idx >> 9), f = (int)(idx & 511);
        const float* s = &W_ih[(size_t)j * 2560 + f];
        float4 a = *(const float4*)&s[0], b = *(const float4*)&s[4];
        u16x8 o; o[0]=bf_rne(a.x); o[1]=bf_rne(a.y); o[2]=bf_rne(a.z); o[3]=bf_rne(a.w);
        o[4]=bf_rne(b.x); o[5]=bf_rne(b.y); o[6]=bf_rne(b.z); o[7]=bf_rne(b.w);
        *(u16x8*)&WihEB[idx] = o;
    } else if (blk < 12484) {               // WhhT[k][j] = bf16(W_hh[j][k]) [512][2048]
        int k = blk - 11972, j0 = tid * 8;
        u16x8 o;
#pragma unroll
        for (int q = 0; q < 8; q++) o[q] = bf_rne(W_hh[(size_t)(j0 + q) * 512 + k]);
        *(u16x8*)&WhhT[(size_t)k * 2048 + j0] = o;
    } else if (blk < 13124) {               // XB[m] = bf16(emb[captions]), m = t*32+b
        int m = blk - 12484;
        int tt = m >> 5, b = m & 31;
        int cap = captions[b * T_ + tt];
        int i = tid * 2;
        u16x2 o;
        o[0] = bf_rne(emb[(size_t)cap * 512 + i]);
        o[1] = bf_rne(emb[(size_t)cap * 512 + i + 1]);
        *(u16x2*)&XB[(size_t)m * 512 + i] = o;
    } else {                                // bsum + zbuf
        int i = tid * 8;
#pragma unroll
        for (int q = 0; q < 8; q++) {
            bsum[i + q] = b_ih[i + q] + b_hh[i + q];
            zbuf[i + q] = 0.f;
        }
    }
}

// ---------------------------------------------------------------------------
// bf16 MFMA GEMM: C[m,n] = A[m,:].B[n,:] + bias[n], A/B bf16 K-major.
// 128x128 tile, 4 waves, 4x4 of 16x16x32 MFMA per wave.
// mode 0: bf16 store.  mode 1: f32 store, crow=(m&31)*20+(m>>5), guard n<N.
// mode 2: f32 store plain.
// ---------------------------------------------------------------------------
__global__ __launch_bounds__(256)
void mfma_gemm_kernel(const ushort_t* __restrict__ A, const ushort_t* __restrict__ B,
                      const float* __restrict__ bias, ushort_t* __restrict__ Cb,
                      float* __restrict__ Cf, int K, int N, int mode)
{
    __shared__ ushort_t As[128][32];
    __shared__ ushort_t Bs[128][32];
    const int tid = threadIdx.x;
    const int m0 = blockIdx.x * 128, n0 = blockIdx.y * 128;
    const int wave = tid >> 6, lane = tid & 63;
    const int wm = (wave & 1) * 64, wn = (wave >> 1) * 64;
    const int lm = lane & 15, lk = (lane >> 4) * 8;

    f32x4 acc[4][4];
#pragma unroll
    for (int mt = 0; mt < 4; mt++)
#pragma unroll
        for (int nt = 0; nt < 4; nt++)
#pragma unroll
            for (int r = 0; r < 4; r++) acc[mt][nt][r] = 0.f;

    for (int k0 = 0; k0 < K; k0 += 32) {
#pragma unroll
        for (int i = 0; i < 2; i++) {
            int gi  = tid + i * 256;
            int row = gi >> 2;
            int gr  = (gi & 3) * 8;
            *(u16x8*)&As[row][gr] = *(const u16x8*)&A[(size_t)(m0 + row) * K + k0 + gr];
            int brow = n0 + row; if (brow >= N) brow = N - 1;
            *(u16x8*)&Bs[row][gr] = *(const u16x8*)&B[(size_t)brow * K + k0 + gr];
        }
        __syncthreads();
        bf16x8 af[4], bv[4];
#pragma unroll
        for (int mt = 0; mt < 4; mt++)
            af[mt] = *(const bf16x8*)&As[wm + mt * 16 + lm][lk];
#pragma unroll
        for (int nt = 0; nt < 4; nt++)
            bv[nt] = *(const bf16x8*)&Bs[wn + nt * 16 + lm][lk];
#pragma unroll
        for (int mt = 0; mt < 4; mt++)
#pragma unroll
            for (int nt = 0; nt < 4; nt++)
                acc[mt][nt] = __builtin_amdgcn_mfma_f32_16x16x32_bf16(
                    af[mt], bv[nt], acc[mt][nt], 0, 0, 0);
        __syncthreads();
    }

    const int rb = (lane >> 4) * 4;
#pragma unroll
    for (int nt = 0; nt < 4; nt++) {
        int n = n0 + wn + nt * 16 + lm;
        int nc = n < N ? n : N - 1;
        float bz = bias[nc];
#pragma unroll
        for (int mt = 0; mt < 4; mt++) {
            int mbase = m0 + wm + mt * 16 + rb;
#pragma unroll
            for (int r = 0; r < 4; r++) {
                float v = acc[mt][nt][r] + bz;
                int m = mbase + r;
                if (mode == 0) {
                    Cb[(size_t)m * N + n] = bf_rne(v);
                } else if (n < N) {
                    int crow = (mode == 1) ? ((m & 31) * 20 + (m >> 5)) : m;
                    Cf[(size_t)crow * N + n] = v;
                }
            }
        }
    }
}

// ---------------------------------------------------------------------------
// Per-b producer/consumer sync. Each b owns its own 128 B line in flagA/cntB.
// Poll RELAXED (+s_sleep backoff) to avoid per-poll cache invalidation storms;
// one ACQUIRE load on exit for cross-XCD visibility of the produced data.
// ---------------------------------------------------------------------------
__device__ __forceinline__ void wait_eq(unsigned* p, unsigned target) {
    if (threadIdx.x == 0) {
        while (__hip_atomic_load(p, __ATOMIC_RELAXED, __HIP_MEMORY_SCOPE_AGENT) != target)
            __builtin_amdgcn_s_sleep(4);
        (void)__hip_atomic_load(p, __ATOMIC_ACQUIRE, __HIP_MEMORY_SCOPE_AGENT);
    }
    __syncthreads();
}

// ---------------------------------------------------------------------------
// Persistent 20-step decoder. 160 blocks = 32 groups x (1 leader + 4 peers).
// Leader (s=0), per t: pointwise h_t (c in regs) -> hF/hseqB, dec_proj,
//   energies, softmax -> alpha; release flagA[b][t]. Next iter waits
//   cntB[b][t-1]==4 before consuming gbuf.
// Peer (s=1..4), per t: wait flagA[b][t]; stage alpha/h to LDS; compute
//   512-j slice: g = xproj(t,b,j) + sum_k WhhT[k][j] h[k] + sum_p al[p] G[b][p][j];
//   write gbuf; release-increment cntB[b][t].
// All sync is per-b: <=5 agents per cache line.
// ---------------------------------------------------------------------------
__global__ __launch_bounds__(256, 2)
void persist_kernel(float* __restrict__ gbuf,           // [32][2048]
                    float* __restrict__ hF,             // [32][512]
                    ushort_t* __restrict__ hseqB,       // [21][32][512]
                    const ushort_t* __restrict__ encPB, // [6272][512]
                    const ushort_t* __restrict__ decWB, // [512][512]
                    const float* __restrict__ dec_b,
                    const float* __restrict__ full_W,
                    const float* __restrict__ full_b,
                    float* __restrict__ alpha,          // [32][200]
                    const ushort_t* __restrict__ GB,    // [6272][2048]
                    const ushort_t* __restrict__ WhhT,  // [512][2048]
                    const float* __restrict__ xproj,    // [640][2048]
                    unsigned* __restrict__ flagA,       // [32][32]
                    unsigned* __restrict__ cntB)        // [32][32]
{
    __shared__ float hs[512];
    __shared__ float fws[512];
    __shared__ float dps[512];
    __shared__ float es[200];
    __shared__ float al[200];
    __shared__ float hsh[512];

    const int tid = threadIdx.x;
    const int b = blockIdx.x / GSZ;
    const int s = blockIdx.x % GSZ;

    if (s == 0) {
        // ============================ LEADER ============================
        float c0 = 0.f, c1 = 0.f;
        if (tid < 128)
            *(float4*)&fws[tid * 4] = *(const float4*)&full_W[tid * 4];

        for (int t = 0; t <= T_; t++) {
            if (t > 0) wait_eq(&cntB[b * 32 + (t - 1)], 4);

            if (t == 0) {
#pragma unroll
                for (int it = 0; it < 2; it++) {
                    int u = tid + it * 256;
                    hs[u] = 0.f;
                    hF[b * 512 + u] = 0.f;
                }
            } else {
#pragma unroll
                for (int it = 0; it < 2; it++) {
                    int u = tid + it * 256;
                    float gi = gbuf[b * 2048 + u];
                    float gf = gbuf[b * 2048 + 512 + u];
                    float gg = gbuf[b * 2048 + 1024 + u];
                    float go = gbuf[b * 2048 + 1536 + u];
                    float ig = 1.f / (1.f + expf(-gi));
                    float fg = 1.f / (1.f + expf(-gf));
                    float g_ = tanhf(gg);
                    float og = 1.f / (1.f + expf(-go));
                    float cold = it ? c1 : c0;
                    float cn = fg * cold + ig * g_;
                    float hn = og * tanhf(cn);
                    if (it) c1 = cn; else c0 = cn;
                    hs[u] = hn;
                    hF[b * 512 + u] = hn;
                    hseqB[(size_t)t * 16384 + b * 512 + u] = bf_rne(hn);
                }
            }
            if (t == T_) break;
            __syncthreads();

            const int lane = tid & 63, wave = tid >> 6;
            const int g16 = lane >> 4, gl = lane & 15;
            // dps = h . dec_W^T + dec_b
#pragma unroll 4
            for (int q = 0; q < 32; q++) {
                int a = wave * 128 + q * 4 + g16;
                const ushort_t* wr = decWB + (size_t)a * 512;
                float sacc = 0.f;
#pragma unroll
                for (int jj = 0; jj < 4; jj++) {
                    u16x8 wv = *(const u16x8*)&wr[jj * 128 + gl * 8];
                    float4 h0 = *(float4*)&hs[jj * 128 + gl * 8];
                    float4 h1 = *(float4*)&hs[jj * 128 + gl * 8 + 4];
                    sacc += b2f(wv[0]) * h0.x + b2f(wv[1]) * h0.y
                          + b2f(wv[2]) * h0.z + b2f(wv[3]) * h0.w
                          + b2f(wv[4]) * h1.x + b2f(wv[5]) * h1.y
                          + b2f(wv[6]) * h1.z + b2f(wv[7]) * h1.w;
                }
                sacc += __shfl_xor(sacc, 1, 64); sacc += __shfl_xor(sacc, 2, 64);
                sacc += __shfl_xor(sacc, 4, 64); sacc += __shfl_xor(sacc, 8, 64);
                if (gl == 0) dps[a] = sacc + dec_b[a];
            }
            __syncthreads();
            // energies
            const float fb0 = full_b[0];
            for (int i = 0; i < 13; i++) {
                int q = wave + 4 * i;
                if (q >= 49) break;
                int p = q * 4 + g16;
                const ushort_t* ep = encPB + ((size_t)(b * P_) + p) * 512;
                float sacc = 0.f;
#pragma unroll
                for (int jj = 0; jj < 4; jj++) {
                    u16x8 ev = *(const u16x8*)&ep[jj * 128 + gl * 8];
                    float4 d0 = *(float4*)&dps[jj * 128 + gl * 8];
                    float4 d1 = *(float4*)&dps[jj * 128 + gl * 8 + 4];
                    float4 f0 = *(float4*)&fws[jj * 128 + gl * 8];
                    float4 f1 = *(float4*)&fws[jj * 128 + gl * 8 + 4];
                    sacc += fmaxf(b2f(ev[0]) + d0.x, 0.f) * f0.x
                          + fmaxf(b2f(ev[1]) + d0.y, 0.f) * f0.y
                          + fmaxf(b2f(ev[2]) + d0.z, 0.f) * f0.z
                          + fmaxf(b2f(ev[3]) + d0.w, 0.f) * f0.w
                          + fmaxf(b2f(ev[4]) + d1.x, 0.f) * f1.x
                          + fmaxf(b2f(ev[5]) + d1.y, 0.f) * f1.y
                          + fmaxf(b2f(ev[6]) + d1.z, 0.f) * f1.z
                          + fmaxf(b2f(ev[7]) + d1.w, 0.f) * f1.w;
                }
                sacc += __shfl_xor(sacc, 1, 64); sacc += __shfl_xor(sacc, 2, 64);
                sacc += __shfl_xor(sacc, 4, 64); sacc += __shfl_xor(sacc, 8, 64);
                if (gl == 0) es[p] = sacc + fb0;
            }
            __syncthreads();
            // softmax (wave 0) -> alpha (global)
            if (tid < 64) {
                float v[4]; int pv[4]; int n = 0;
                for (int q = 0; q < 4; q++) {
                    int p = tid + 64 * q;
                    if (p < P_) { pv[n] = p; v[n] = es[p]; n++; }
                }
                float m = -1e30f;
                for (int q = 0; q < n; q++) m = fmaxf(m, v[q]);
#pragma unroll
                for (int off = 32; off > 0; off >>= 1) m = fmaxf(m, __shfl_xor(m, off, 64));
                float ssum = 0.f;
                for (int q = 0; q < n; q++) { v[q] = expf(v[q] - m); ssum += v[q]; }
#pragma unroll
                for (int off = 32; off > 0; off >>= 1) ssum += __shfl_xor(ssum, off, 64);
                float rinv = 1.f / ssum;
                for (int q = 0; q < n; q++) alpha[b * 200 + pv[q]] = v[q] * rinv;
            }
            __syncthreads();
            if (tid == 0)
                __hip_atomic_store(&flagA[b * 32 + t], 1u,
                                   __ATOMIC_RELEASE, __HIP_MEMORY_SCOPE_AGENT);
        }
    } else {
        // ============================ PEER ============================
        const int j = (s - 1) * 512 + tid * 2;
        const size_t gbase = (size_t)(b * P_) * 2048 + j;
        const ushort_t* wt = WhhT + j;

        for (int t = 0; t < T_; t++) {
            wait_eq(&flagA[b * 32 + t], 1);
            if (tid < P_) al[tid] = alpha[b * 200 + tid];
            *(float2*)&hsh[tid * 2] = *(const float2*)&hF[b * 512 + tid * 2];
            __syncthreads();

            float2 xp = *(const float2*)&xproj[(size_t)(t * 32 + b) * 2048 + j];
            float acc0 = xp.x, acc1 = xp.y;
#pragma unroll 8
            for (int k = 0; k < 512; k++) {
                u16x2 wv = *(const u16x2*)&wt[(size_t)k * 2048];
                float hv = hsh[k];
                acc0 += b2f(wv[0]) * hv;
                acc1 += b2f(wv[1]) * hv;
            }
#pragma unroll 4
            for (int p = 0; p < P_; p++) {
                u16x2 gv = *(const u16x2*)&GB[gbase + (size_t)p * 2048];
                float av = al[p];
                acc0 += b2f(gv[0]) * av;
                acc1 += b2f(gv[1]) * av;
            }
            float2 o; o.x = acc0; o.y = acc1;
            *(float2*)&gbuf[b * 2048 + j] = o;
            __syncthreads();
            if (tid == 0)
                __hip_atomic_fetch_add(&cntB[b * 32 + t], 1u,
                                       __ATOMIC_RELEASE, __HIP_MEMORY_SCOPE_AGENT);
        }
    }
}

// ---------------------------------------------------------------------------
extern "C" void kernel_launch(void* const* d_in, const int* in_sizes, int n_in,
                              void* d_out, int out_size, void* d_ws, size_t ws_size,
                              hipStream_t stream)
{
    (void)in_sizes; (void)n_in; (void)out_size; (void)ws_size;
    const float* feat   = (const float*)d_in[0];
    const int*   caps   = (const int*)  d_in[1];
    const float* emb    = (const float*)d_in[2];
    const float* W_ih   = (const float*)d_in[3];
    const float* b_ih   = (const float*)d_in[4];
    const float* W_hh   = (const float*)d_in[5];
    const float* b_hh   = (const float*)d_in[6];
    const float* fc_W   = (const float*)d_in[7];
    const float* fc_b   = (const float*)d_in[8];
    const float* enc_W  = (const float*)d_in[9];
    const float* enc_b  = (const float*)d_in[10];
    const float* dec_W  = (const float*)d_in[11];
    const float* dec_b  = (const float*)d_in[12];
    const float* full_W = (const float*)d_in[13];
    const float* full_b = (const float*)d_in[14];
    float* out = (float*)d_out;

    // workspace carve (~90 MB), 128B-aligned chunks
    char* w = (char*)d_ws;
    ushort_t* featB = (ushort_t*)w;              w += 25690112;  // [6272][2048]
    ushort_t* encWB = (ushort_t*)w;              w += 2097152;   // [512][2048]
    ushort_t* fcWB  = (ushort_t*)w;              w += 10240000;  // [10000][512]
    ushort_t* decWB = (ushort_t*)w;              w += 524288;    // [512][512]
    ushort_t* WihCB = (ushort_t*)w;              w += 8388608;   // [2048][2048]
    ushort_t* WihEB = (ushort_t*)w;              w += 2097152;   // [2048][512]
    ushort_t* WhhT  = (ushort_t*)w;              w += 2097152;   // [512][2048]
    ushort_t* XB    = (ushort_t*)w;              w += 655360;    // [640][512]
    ushort_t* encPB = (ushort_t*)w;              w += 6422528;   // [6272][512]
    ushort_t* GB    = (ushort_t*)w;              w += 25690112;  // [6272][2048]
    float*    xproj = (float*)w;                 w += 5242880;   // [640][2048]
    float*    bsum  = (float*)w;                 w += 8192;      // [2048]
    float*    zbuf  = (float*)w;                 w += 8192;      // [2048]
    float*    hF    = (float*)w;                 w += 65536;     // [32][512]
    ushort_t* hseqB = (ushort_t*)w;              w += 688128;    // [21][32][512]
    float*    gbuf  = (float*)w;                 w += 262144;    // [32][2048]
    float*    alpha = (float*)w;                 w += 25600;     // [32][200]
    unsigned* flagA = (unsigned*)w;              w += 4096;      // [32][32]
    unsigned* cntB  = (unsigned*)w;              w += 4096;      // [32][32]

    // zero per-b sync flags (contiguous 8 KB; ws re-poisoned each replay)
    hipMemsetAsync(flagA, 0, 8192, stream);

    // one-time converts / extracts / transposes / gathers (1 node)
    cvt_all_kernel<<<13125, 256, 0, stream>>>(
        feat, enc_W, fc_W, dec_W, W_ih, W_hh, emb, caps, b_ih, b_hh,
        featB, encWB, fcWB, decWB, WihCB, WihEB, WhhT, XB, bsum, zbuf);

    // enc_proj: [6272,2048]x[512,2048]^T -> encPB bf16
    mfma_gemm_kernel<<<dim3(49, 4), 256, 0, stream>>>(
        featB, encWB, enc_b, encPB, nullptr, 2048, 512, 0);

    // G = feat . W_ih[:,512:]^T : [6272,2048]x[2048,2048]^T -> GB bf16
    mfma_gemm_kernel<<<dim3(49, 16), 256, 0, stream>>>(
        featB, WihCB, zbuf, GB, nullptr, 2048, 2048, 0);

    // xproj = X . W_ih[:,:512]^T + (b_ih+b_hh): [640,512]x[2048,512]^T -> f32
    mfma_gemm_kernel<<<dim3(5, 16), 256, 0, stream>>>(
        XB, WihEB, bsum, nullptr, xproj, 512, 2048, 2);

    // persistent 20-step recurrent loop (1 node, per-b sync only)
    persist_kernel<<<NBLK, 256, 0, stream>>>(
        gbuf, hF, hseqB, encPB, decWB, dec_b, full_W, full_b,
        alpha, GB, WhhT, xproj, flagA, cntB);

    // batched vocab FC: [640,512]x[10000,512]^T -> out (f32, remapped rows)
    mfma_gemm_kernel<<<dim3(5, 79), 256, 0, stream>>>(
        hseqB + 16384, fcWB, fc_b, nullptr, out, 512, V_, 1);
}